// Round 3
// baseline (1351.021 us; speedup 1.0000x reference)
//
#include <hip/hip_runtime.h>
#include <hip/hip_bf16.h>

typedef __bf16 bvec8 __attribute__((ext_vector_type(8)));
typedef float fvec4 __attribute__((ext_vector_type(4)));

#define E_ 4
#define F_ 16
#define O_ 9
#define B_ 512
#define DIN_ 32
#define H_ 4
#define DK_ 32
#define DH_ 128
#define FINAL_ 17
#define EF_ 64
#define EFO_ 576

// ---------------- transpose+downcast prep: in fp32 [batch][R][C] -> out bf16 [batch][C][R] ----------------
__global__ __launch_bounds__(256) void transpose_k(const float* __restrict__ in,
                                                   __bf16* __restrict__ out, int R, int C) {
  __shared__ float tile[64 * 65];
  int r0 = blockIdx.y * 64, c0 = blockIdx.x * 64;
  const float* src = in + (size_t)blockIdx.z * R * C;
  __bf16* dst = out + (size_t)blockIdx.z * R * C;
  for (int idx = threadIdx.x; idx < 4096; idx += 256) {
    int r = idx >> 6, c = idx & 63;
    if ((r0 + r) < R && (c0 + c) < C)
      tile[r * 65 + c] = src[(size_t)(r0 + r) * C + (c0 + c)];
  }
  __syncthreads();
  for (int idx = threadIdx.x; idx < 4096; idx += 256) {
    int c = idx >> 6, r = idx & 63;
    if ((r0 + r) < R && (c0 + c) < C)
      dst[(size_t)(c0 + c) * R + (r0 + r)] = (__bf16)tile[r * 65 + c];
  }
}

// ---------------- shared GEMM helpers ----------------
// LDS tile layout: panels [K/32][128 rows][32 k], fragments read as contiguous 16B.
__device__ __forceinline__ void stage_tile(const __bf16* __restrict__ g, int ldg,
                                           __bf16* s, int cols) {
  int cpr = cols >> 3;
  int nch = 128 * cpr;
  for (int c = threadIdx.x; c < nch; c += 256) {
    int r = c / cpr;
    int cc = (c - r * cpr) << 3;
    *(uint4*)(s + ((cc >> 5) * 128 + r) * 32 + (cc & 31)) =
        *(const uint4*)(g + (size_t)r * ldg + cc);
  }
}

// fp32 global source -> bf16 LDS tile (same layout)
__device__ __forceinline__ void stage_tile_f32(const float* __restrict__ g, int ldg,
                                               __bf16* s, int cols) {
  int cpr = cols >> 3;
  int nch = 128 * cpr;
  for (int c = threadIdx.x; c < nch; c += 256) {
    int r = c / cpr;
    int cc = (c - r * cpr) << 3;
    const float* gp = g + (size_t)r * ldg + cc;
    float4 f0 = *(const float4*)gp;
    float4 f1 = *(const float4*)(gp + 4);
    bvec8 bv;
    bv[0] = (__bf16)f0.x; bv[1] = (__bf16)f0.y; bv[2] = (__bf16)f0.z; bv[3] = (__bf16)f0.w;
    bv[4] = (__bf16)f1.x; bv[5] = (__bf16)f1.y; bv[6] = (__bf16)f1.z; bv[7] = (__bf16)f1.w;
    *(bvec8*)(s + ((cc >> 5) * 128 + r) * 32 + (cc & 31)) = bv;
  }
}

__device__ __forceinline__ void gemm128(const __bf16* As, const __bf16* Ws, int K,
                                        fvec4 acc[4][4], int wm, int wn, int lm, int q8) {
  for (int k0 = 0; k0 < K; k0 += 32) {
    const __bf16* ap = As + (k0 >> 5) * 4096 + q8;
    const __bf16* bp = Ws + (k0 >> 5) * 4096 + q8;
    bvec8 a[4], b[4];
#pragma unroll
    for (int i = 0; i < 4; i++) a[i] = *(const bvec8*)(ap + (wm + i * 16 + lm) * 32);
#pragma unroll
    for (int j = 0; j < 4; j++) b[j] = *(const bvec8*)(bp + (wn + j * 16 + lm) * 32);
#pragma unroll
    for (int i = 0; i < 4; i++)
#pragma unroll
      for (int j = 0; j < 4; j++)
        acc[i][j] = __builtin_amdgcn_mfma_f32_16x16x32_bf16(a[i], b[j], acc[i][j], 0, 0, 0);
  }
}

// ---------------- K1: fused 2-layer per-object MLP ----------------
__global__ __launch_bounds__(256) void mlp_kernel(const float* __restrict__ x,
    const __bf16* __restrict__ fw1t, const float* __restrict__ fb1,
    const __bf16* __restrict__ fw2t, const float* __restrict__ fb2,
    __bf16* __restrict__ h0) {
  __shared__ __align__(16) __bf16 smem[32768];
  int efo = blockIdx.y, mt = blockIdx.x;
  int t = threadIdx.x, l = t & 63, w = t >> 6;
  int wm = (w & 1) * 64, wn = (w >> 1) * 64;
  int lm = l & 15, q8 = (l >> 4) * 8, qr = (l >> 4) * 4;
  __bf16* xs = smem;          // [1][128][32]
  __bf16* w1s = smem + 4096;  // [1][128][32]
  stage_tile_f32(x + ((size_t)efo * B_ + mt * 128) * DIN_, DIN_, xs, DIN_);
  stage_tile(fw1t + (size_t)efo * DH_ * DIN_, DIN_, w1s, DIN_);
  __syncthreads();
  fvec4 zero4 = {0.f, 0.f, 0.f, 0.f};
  fvec4 acc[4][4];
#pragma unroll
  for (int i = 0; i < 4; i++)
#pragma unroll
    for (int j = 0; j < 4; j++) acc[i][j] = zero4;
  gemm128(xs, w1s, 32, acc, wm, wn, lm, q8);
  __syncthreads();
  __bf16* h1s = smem;          // [4][128][32]
  __bf16* w2s = smem + 16384;  // [4][128][32]
  float bias[4];
#pragma unroll
  for (int j = 0; j < 4; j++) bias[j] = fb1[efo * DH_ + wn + j * 16 + lm];
#pragma unroll
  for (int i = 0; i < 4; i++)
#pragma unroll
    for (int j = 0; j < 4; j++)
#pragma unroll
      for (int r = 0; r < 4; r++) {
        float v = fmaxf(acc[i][j][r] + bias[j], 0.f);
        int row = wm + i * 16 + qr + r, col = wn + j * 16 + lm;
        h1s[((col >> 5) * 128 + row) * 32 + (col & 31)] = (__bf16)v;
      }
  stage_tile(fw2t + (size_t)efo * DH_ * DH_, DH_, w2s, DH_);
  __syncthreads();
#pragma unroll
  for (int i = 0; i < 4; i++)
#pragma unroll
    for (int j = 0; j < 4; j++) acc[i][j] = zero4;
  gemm128(h1s, w2s, 128, acc, wm, wn, lm, q8);
#pragma unroll
  for (int j = 0; j < 4; j++) bias[j] = fb2[efo * DH_ + wn + j * 16 + lm];
#pragma unroll
  for (int i = 0; i < 4; i++)
#pragma unroll
    for (int j = 0; j < 4; j++)
#pragma unroll
      for (int r = 0; r < 4; r++) {
        float v = fmaxf(acc[i][j][r] + bias[j], 0.f);
        int row = wm + i * 16 + qr + r, col = wn + j * 16 + lm;
        h0[((size_t)efo * B_ + mt * 128 + row) * DH_ + col] = (__bf16)v;
      }
}

// ---------------- K2: single head-projection GEMM (h -> q|k|v in head layout) ----------------
__global__ __launch_bounds__(256) void headproj_kernel(const __bf16* __restrict__ hsrc,
    const __bf16* __restrict__ wt, __bf16* __restrict__ dst) {
  __shared__ __align__(16) __bf16 smem[32768];
  int efo = blockIdx.y, mt = blockIdx.x;
  int ef = efo / O_, o = efo - ef * O_;
  int t = threadIdx.x, l = t & 63, w = t >> 6;
  int wm = (w & 1) * 64, wn = (w >> 1) * 64;
  int lm = l & 15, q8 = (l >> 4) * 8, qr = (l >> 4) * 4;
  __bf16* hs = smem;
  __bf16* wsm = smem + 16384;
  stage_tile(hsrc + ((size_t)efo * B_ + mt * 128) * DH_, DH_, hs, DH_);
  stage_tile(wt + (size_t)efo * DH_ * DH_, DH_, wsm, DH_);
  __syncthreads();
  fvec4 zero4 = {0.f, 0.f, 0.f, 0.f};
  fvec4 acc[4][4];
#pragma unroll
  for (int i = 0; i < 4; i++)
#pragma unroll
    for (int j = 0; j < 4; j++) acc[i][j] = zero4;
  gemm128(hs, wsm, 128, acc, wm, wn, lm, q8);
#pragma unroll
  for (int i = 0; i < 4; i++)
#pragma unroll
    for (int j = 0; j < 4; j++)
#pragma unroll
      for (int r = 0; r < 4; r++) {
        int row = wm + i * 16 + qr + r, col = wn + j * 16 + lm;
        int hh = col >> 5, d = col & 31, b = mt * 128 + row;
        dst[((((size_t)ef * H_ + hh) * O_ + o) * B_ + b) * DK_ + d] =
            (__bf16)acc[i][j][r];
      }
}

// ---------------- K3: scores + softmax -> P (normalized, bf16) ----------------
__global__ __launch_bounds__(256) void score_kernel(const __bf16* __restrict__ q,
    const __bf16* __restrict__ k, __bf16* __restrict__ P) {
  int t = threadIdx.x;
  int g = t >> 2, sub = t & 3;
  int blk = blockIdx.x;
  int bt = blk & 7, efh = blk >> 3;
  int b = bt * 64 + g, d0 = sub * 8;
  size_t base = (size_t)efh * O_ * B_ * DK_ + (size_t)b * DK_ + d0;
  const size_t ostr = (size_t)B_ * DK_;
  bvec8 kr[9];
#pragma unroll
  for (int o = 0; o < 9; o++) kr[o] = *(const bvec8*)(k + base + (size_t)o * ostr);
  const float scale = 0.17677669529663687f;  // 1/sqrt(32)
  size_t pbase = ((size_t)efh * B_ + b) * 81;
#pragma unroll 1
  for (int oq = 0; oq < 9; oq++) {
    bvec8 qv = *(const bvec8*)(q + base + (size_t)oq * ostr);
    float qf[8];
#pragma unroll
    for (int j = 0; j < 8; j++) qf[j] = (float)qv[j];
    float lg[9];
#pragma unroll
    for (int ok = 0; ok < 9; ok++) {
      float s = 0.f;
#pragma unroll
      for (int j = 0; j < 8; j++) s += qf[j] * (float)kr[ok][j];
      s += __shfl_xor(s, 1);
      s += __shfl_xor(s, 2);
      lg[ok] = s * scale;
    }
    float mx = lg[0];
#pragma unroll
    for (int ok = 1; ok < 9; ok++) mx = fmaxf(mx, lg[ok]);
    float sum = 0.f;
#pragma unroll
    for (int ok = 0; ok < 9; ok++) { lg[ok] = __expf(lg[ok] - mx); sum += lg[ok]; }
    float inv = 1.f / sum;
    for (int ok = sub; ok < 9; ok += 4)
      P[pbase + oq * 9 + ok] = (__bf16)(lg[ok] * inv);
  }
}

// ---------------- K4: apply P to V ----------------
__global__ __launch_bounds__(256) void apply_kernel(const __bf16* __restrict__ P,
    const __bf16* __restrict__ v, __bf16* __restrict__ a) {
  int t = threadIdx.x;
  int g = t >> 2, sub = t & 3;
  int blk = blockIdx.x;
  int bt = blk & 7, efh = blk >> 3;
  int b = bt * 64 + g, d0 = sub * 8;
  size_t base = (size_t)efh * O_ * B_ * DK_ + (size_t)b * DK_ + d0;
  const size_t ostr = (size_t)B_ * DK_;
  bvec8 vr[9];
#pragma unroll
  for (int o = 0; o < 9; o++) vr[o] = *(const bvec8*)(v + base + (size_t)o * ostr);
  size_t pbase = ((size_t)efh * B_ + b) * 81;
#pragma unroll 1
  for (int oq = 0; oq < 9; oq++) {
    float pw[9];
#pragma unroll
    for (int ok = 0; ok < 9; ok++) pw[ok] = (float)P[pbase + oq * 9 + ok];
    float oacc[8] = {0.f, 0.f, 0.f, 0.f, 0.f, 0.f, 0.f, 0.f};
#pragma unroll
    for (int ok = 0; ok < 9; ok++)
#pragma unroll
      for (int j = 0; j < 8; j++) oacc[j] += pw[ok] * (float)vr[ok][j];
    bvec8 ov;
#pragma unroll
    for (int j = 0; j < 8; j++) ov[j] = (__bf16)oacc[j];
    *(bvec8*)(a + base + (size_t)oq * ostr) = ov;
  }
}

// ---------------- K5: out-proj + residual + post-FC (fused; hout may alias resid) ----------------
__global__ __launch_bounds__(256) void proj_kernel(const __bf16* __restrict__ ain,
    const __bf16* __restrict__ wot, const __bf16* __restrict__ pwt,
    const float* __restrict__ pb, const __bf16* resid,
    __bf16* hout) {
  __shared__ __align__(16) __bf16 smem[32768];
  int efo = blockIdx.y, mt = blockIdx.x;
  int ef = efo / O_, o = efo - ef * O_;
  int t = threadIdx.x, l = t & 63, w = t >> 6;
  int wm = (w & 1) * 64, wn = (w >> 1) * 64;
  int lm = l & 15, q8 = (l >> 4) * 8, qr = (l >> 4) * 4;
  __bf16* as2 = smem;
  __bf16* wsm = smem + 16384;
#pragma unroll
  for (int hh = 0; hh < 4; hh++)
    stage_tile(ain + ((((size_t)ef * H_ + hh) * O_ + o) * B_ + mt * 128) * DK_, DK_,
               as2 + hh * 4096, DK_);
  stage_tile(wot + (size_t)efo * DH_ * DH_, DH_, wsm, DH_);
  __syncthreads();
  fvec4 zero4 = {0.f, 0.f, 0.f, 0.f};
  fvec4 acc[4][4];
#pragma unroll
  for (int i = 0; i < 4; i++)
#pragma unroll
    for (int j = 0; j < 4; j++) acc[i][j] = zero4;
  gemm128(as2, wsm, 128, acc, wm, wn, lm, q8);
  // residual add (fp32); tile is block-private and read-before-write per thread,
  // so in-place hout==resid is safe
#pragma unroll
  for (int i = 0; i < 4; i++)
#pragma unroll
    for (int j = 0; j < 4; j++)
#pragma unroll
      for (int r = 0; r < 4; r++) {
        int row = wm + i * 16 + qr + r, col = wn + j * 16 + lm;
        acc[i][j][r] +=
            (float)resid[((size_t)efo * B_ + mt * 128 + row) * DH_ + col];
      }
  __syncthreads();
#pragma unroll
  for (int i = 0; i < 4; i++)
#pragma unroll
    for (int j = 0; j < 4; j++)
#pragma unroll
      for (int r = 0; r < 4; r++) {
        int row = wm + i * 16 + qr + r, col = wn + j * 16 + lm;
        as2[((col >> 5) * 128 + row) * 32 + (col & 31)] = (__bf16)acc[i][j][r];
      }
  stage_tile(pwt + (size_t)efo * DH_ * DH_, DH_, wsm, DH_);
  __syncthreads();
#pragma unroll
  for (int i = 0; i < 4; i++)
#pragma unroll
    for (int j = 0; j < 4; j++) acc[i][j] = zero4;
  gemm128(as2, wsm, 128, acc, wm, wn, lm, q8);
  float bias[4];
#pragma unroll
  for (int j = 0; j < 4; j++) bias[j] = pb[efo * DH_ + wn + j * 16 + lm];
#pragma unroll
  for (int i = 0; i < 4; i++)
#pragma unroll
    for (int j = 0; j < 4; j++)
#pragma unroll
      for (int r = 0; r < 4; r++) {
        float vv = fmaxf(acc[i][j][r] + bias[j], 0.f);
        int row = wm + i * 16 + qr + r, col = wn + j * 16 + lm;
        hout[((size_t)efo * B_ + mt * 128 + row) * DH_ + col] = (__bf16)vv;
      }
}

// ---------------- K6: mean-pool over objects ----------------
__global__ __launch_bounds__(256) void pool_kernel(const __bf16* __restrict__ h2,
                                                   __bf16* __restrict__ pooled) {
  size_t idx = ((size_t)blockIdx.x * 256 + threadIdx.x) * 8;
  int ef = (int)(idx >> 16);  // B_*DH_ = 65536 per (e,f)
  int rem = (int)(idx & 65535);
  float accv[8] = {0.f, 0.f, 0.f, 0.f, 0.f, 0.f, 0.f, 0.f};
#pragma unroll
  for (int o = 0; o < 9; o++) {
    bvec8 tv = *(const bvec8*)(h2 + (size_t)(ef * O_ + o) * B_ * DH_ + rem);
#pragma unroll
    for (int j = 0; j < 8; j++) accv[j] += (float)tv[j];
  }
  const float inv9 = 1.f / 9.f;
  bvec8 ov;
#pragma unroll
  for (int j = 0; j < 8; j++) ov[j] = (__bf16)(accv[j] * inv9);
  *(bvec8*)(pooled + idx) = ov;
}

// ---------------- K7: predictor (2 GEMMs fused), fp32 output ----------------
__global__ __launch_bounds__(256) void pred_kernel(const __bf16* __restrict__ pooled,
    const __bf16* __restrict__ pw1t, const float* __restrict__ pb1,
    const __bf16* __restrict__ pw2t, const float* __restrict__ pb2,
    float* __restrict__ out) {
  __shared__ __align__(16) __bf16 smem[32768];
  int ef = blockIdx.y, mt = blockIdx.x;
  int t = threadIdx.x, l = t & 63, w = t >> 6;
  int wm = (w & 1) * 64, wn = (w >> 1) * 64;
  int lm = l & 15, q8 = (l >> 4) * 8, qr = (l >> 4) * 4;
  __bf16* ps = smem;
  __bf16* wsm = smem + 16384;
  stage_tile(pooled + ((size_t)ef * B_ + mt * 128) * DH_, DH_, ps, DH_);
  stage_tile(pw1t + (size_t)ef * DH_ * DH_, DH_, wsm, DH_);
  __syncthreads();
  fvec4 zero4 = {0.f, 0.f, 0.f, 0.f};
  fvec4 acc[4][4];
#pragma unroll
  for (int i = 0; i < 4; i++)
#pragma unroll
    for (int j = 0; j < 4; j++) acc[i][j] = zero4;
  gemm128(ps, wsm, 128, acc, wm, wn, lm, q8);
  __syncthreads();
  float bias[4];
#pragma unroll
  for (int j = 0; j < 4; j++) bias[j] = pb1[ef * DH_ + wn + j * 16 + lm];
#pragma unroll
  for (int i = 0; i < 4; i++)
#pragma unroll
    for (int j = 0; j < 4; j++)
#pragma unroll
      for (int r = 0; r < 4; r++) {
        float vv = fmaxf(acc[i][j][r] + bias[j], 0.f);
        int row = wm + i * 16 + qr + r, col = wn + j * 16 + lm;
        ps[((col >> 5) * 128 + row) * 32 + (col & 31)] = (__bf16)vv;
      }
  // stage pw2t [17][128] (bf16, transposed) zero-padded to [32][128]
  for (int c = threadIdx.x; c < 512; c += 256) {
    int r = c >> 4, cc = (c & 15) << 3;
    uint4 val;
    val.x = val.y = val.z = val.w = 0u;
    if (r < FINAL_)
      val = *(const uint4*)(pw2t + (size_t)ef * FINAL_ * DH_ + r * DH_ + cc);
    *(uint4*)(wsm + ((cc >> 5) * 32 + r) * 32 + (cc & 31)) = val;
  }
  __syncthreads();
  fvec4 acc2[2][2];
#pragma unroll
  for (int i = 0; i < 2; i++)
#pragma unroll
    for (int j = 0; j < 2; j++) acc2[i][j] = zero4;
  for (int k0 = 0; k0 < 128; k0 += 32) {
    bvec8 a2[2], b2[2];
#pragma unroll
    for (int i = 0; i < 2; i++)
      a2[i] = *(const bvec8*)(ps + ((k0 >> 5) * 128 + w * 32 + i * 16 + lm) * 32 + q8);
#pragma unroll
    for (int j = 0; j < 2; j++)
      b2[j] = *(const bvec8*)(wsm + ((k0 >> 5) * 32 + j * 16 + lm) * 32 + q8);
#pragma unroll
    for (int i = 0; i < 2; i++)
#pragma unroll
      for (int j = 0; j < 2; j++)
        acc2[i][j] = __builtin_amdgcn_mfma_f32_16x16x32_bf16(a2[i], b2[j], acc2[i][j], 0, 0, 0);
  }
#pragma unroll
  for (int i = 0; i < 2; i++)
#pragma unroll
    for (int j = 0; j < 2; j++)
#pragma unroll
      for (int r = 0; r < 4; r++) {
        int col = j * 16 + lm;
        if (col < FINAL_) {
          int b = mt * 128 + w * 32 + i * 16 + qr + r;
          out[((size_t)ef * B_ + b) * FINAL_ + col] =
              acc2[i][j][r] + pb2[ef * FINAL_ + col];
        }
      }
}

// ---------------- host ----------------
extern "C" void kernel_launch(void* const* d_in, const int* in_sizes, int n_in,
                              void* d_out, int out_size, void* d_ws, size_t ws_size,
                              hipStream_t stream) {
  (void)in_sizes; (void)n_in; (void)out_size; (void)ws_size;
  const float* x     = (const float*)d_in[0];
  const float* fb1   = (const float*)d_in[2];
  const float* fb2   = (const float*)d_in[4];
  const float* a0_pb = (const float*)d_in[10];
  const float* a1_pb = (const float*)d_in[16];
  const float* pb1   = (const float*)d_in[18];
  const float* pb2   = (const float*)d_in[20];

  __bf16* wsb = (__bf16*)d_ws;
  const size_t SLOT = (size_t)EFO_ * DH_ * DH_;   // 9,437,184 elems
  const size_t ABUF = (size_t)EFO_ * B_ * DH_;    // 37,748,736 elems
  __bf16* s0 = wsb;
  __bf16* s1 = s0 + SLOT;
  __bf16* s2 = s1 + SLOT;
  __bf16* A0 = s2 + SLOT;       // h (in-place through both attention blocks)
  __bf16* A1 = A0 + ABUF;       // q, then v
  __bf16* A2 = A1 + ABUF;       // k, then attn-out
  __bf16* Pb = A2 + ABUF;       // [EF*H][B][81] bf16 = 21 MB
  // total: 3*SLOT + 3*ABUF + 10,616,832 elems = ~290 MiB

  auto T = [&](const void* src, __bf16* dst, int R, int C, int batch) {
    dim3 g((C + 63) / 64, (R + 63) / 64, batch);
    transpose_k<<<g, 256, 0, stream>>>((const float*)src, dst, R, C);
  };

  dim3 gg(4, EFO_);

  // MLP
  T(d_in[1], s0, DIN_, DH_, EFO_);
  T(d_in[3], s1, DH_, DH_, EFO_);
  mlp_kernel<<<gg, 256, 0, stream>>>(x, s0, fb1, s1, fb2, A0);

  for (int blkI = 0; blkI < 2; blkI++) {
    int wbase = blkI == 0 ? 5 : 11;
    const float* pb = blkI == 0 ? a0_pb : a1_pb;
    T(d_in[wbase + 0], s0, DH_, DH_, EFO_);  // wq
    T(d_in[wbase + 1], s1, DH_, DH_, EFO_);  // wk
    T(d_in[wbase + 2], s2, DH_, DH_, EFO_);  // wv
    headproj_kernel<<<gg, 256, 0, stream>>>(A0, s0, A1);        // q
    headproj_kernel<<<gg, 256, 0, stream>>>(A0, s1, A2);        // k
    score_kernel<<<2048, 256, 0, stream>>>(A1, A2, Pb);         // P
    headproj_kernel<<<gg, 256, 0, stream>>>(A0, s2, A1);        // v (over q)
    apply_kernel<<<2048, 256, 0, stream>>>(Pb, A1, A2);         // attn-out (over k)
    T(d_in[wbase + 3], s0, DH_, DH_, EFO_);  // wo
    T(d_in[wbase + 4], s1, DH_, DH_, EFO_);  // pw
    proj_kernel<<<gg, 256, 0, stream>>>(A2, s0, s1, pb, A0, A0);  // in-place h
  }

  // pool + predictor
  T(d_in[17], s0, DH_, DH_, EF_);
  T(d_in[19], s1, DH_, FINAL_, EF_);
  pool_kernel<<<2048, 256, 0, stream>>>(A0, s2);
  pred_kernel<<<dim3(4, EF_), 256, 0, stream>>>(s2, s0, pb1, s1, pb2,
                                                (float*)d_out);
}